// Round 1
// baseline (453.345 us; speedup 1.0000x reference)
//
#include <hip/hip_runtime.h>
#include <hip/hip_bf16.h>

// Problem constants
// B=64, N=2048, C=256, H=8, Ch=32, M = B*N = 131072
// qkv dim = 768 (s*256 + h*32 + ch)

typedef __attribute__((ext_vector_type(8))) short bf16x8;
typedef __attribute__((ext_vector_type(4))) short bf16x4;
typedef __attribute__((ext_vector_type(4))) float f32x4;

__device__ __forceinline__ short f2bf(float f) {
    unsigned u = __builtin_bit_cast(unsigned, f);
    unsigned r = (u + 0x7FFFu + ((u >> 16) & 1u)) >> 16;  // RNE
    return (short)r;
}
__device__ __forceinline__ float bf2f(short h) {
    unsigned u = ((unsigned)(unsigned short)h) << 16;
    return __builtin_bit_cast(float, u);
}

// ---------------- K0: convert weights fp32 -> bf16 ----------------
__global__ void k0_convert(const float* __restrict__ qkv_w,
                           const float* __restrict__ proj_w,
                           short* __restrict__ wq_bf,
                           short* __restrict__ wp_bf) {
    int i = blockIdx.x * 256 + threadIdx.x;   // grid covers 262144 exactly
    if (i < 196608) {
        wq_bf[i] = f2bf(qkv_w[i]);
    } else {
        int j = i - 196608;
        wp_bf[j] = f2bf(proj_w[j]);
    }
}

// ---------------- K1: fused QKV GEMM + head-attention ----------------
// 512 threads (8 waves), 32 tokens per block.
// Wave w computes qkv cols [96w, 96w+96) for all 32 tokens via
// mfma_f32_16x16x32_bf16 with SWAPPED operands:
//   a_frag = weight rows (n = lane&15), b_frag = token rows (tok = lane&15)
//   -> D: lane reg r holds C[n = nb + (lane>>4)*4 + r][tok = lane&15]
// so each lane writes 4 contiguous bf16 along the qkv dim into LDS Y.
__global__ __launch_bounds__(512, 4) void k1_qkv_attn(
    const float* __restrict__ x,      // [131072][256] fp32
    const short* __restrict__ wq,     // [768][256] bf16 bits
    const float* __restrict__ qkv_b,  // [768] fp32
    short* __restrict__ out2)         // [131072][256] bf16, shuffled layout
{
    __shared__ __align__(16) char smem[49664];  // A tile (16KB) then Y tile (49.6KB)
    const int tid  = threadIdx.x;
    const int lane = tid & 63;
    const int wave = tid >> 6;
    const long t0  = (long)blockIdx.x * 32;

    // ---- stage A: x[t0..t0+32][0..256] fp32 -> bf16 LDS, XOR swizzle ----
    {
        const int r = tid >> 4, s = tid & 15;        // row 0..31, seg 0..15 (16 floats)
        const float4* src = (const float4*)(x + (t0 + r) * 256 + s * 16);
        float ff[16];
        float4 f0 = src[0], f1 = src[1], f2 = src[2], f3 = src[3];
        ff[0]=f0.x; ff[1]=f0.y; ff[2]=f0.z; ff[3]=f0.w;
        ff[4]=f1.x; ff[5]=f1.y; ff[6]=f1.z; ff[7]=f1.w;
        ff[8]=f2.x; ff[9]=f2.y; ff[10]=f2.z; ff[11]=f2.w;
        ff[12]=f3.x; ff[13]=f3.y; ff[14]=f3.z; ff[15]=f3.w;
        bf16x8 v0, v1;
#pragma unroll
        for (int i = 0; i < 8; ++i) { v0[i] = f2bf(ff[i]); v1[i] = f2bf(ff[8 + i]); }
        const int swz = (r & 7) << 4;
        *(bf16x8*)(smem + r * 512 + ((s * 32) ^ swz))      = v0;
        *(bf16x8*)(smem + r * 512 + ((s * 32 + 16) ^ swz)) = v1;
    }
    __syncthreads();

    // ---- MFMA main loop: K = 256 in 8 steps of 32 ----
    f32x4 acc[2][6];
#pragma unroll
    for (int i = 0; i < 2; ++i)
#pragma unroll
        for (int j = 0; j < 6; ++j) acc[i][j] = (f32x4){0.f, 0.f, 0.f, 0.f};

    const int fr = lane & 15, fq = lane >> 4;   // frag row select, k-quarter
    const int nb = wave * 96;                   // this wave's qkv-col base
    const short* wq_base = wq + (nb + fr) * 256 + fq * 8;

#pragma unroll
    for (int ks = 0; ks < 8; ++ks) {
        bf16x8 aW[6], bX[2];
#pragma unroll
        for (int j = 0; j < 6; ++j)
            aW[j] = *(const bf16x8*)(wq_base + j * 16 * 256 + ks * 32);
        const int kbyte = (ks * 32 + fq * 8) * 2;
#pragma unroll
        for (int i = 0; i < 2; ++i) {
            const int row = i * 16 + fr;
            bX[i] = *(const bf16x8*)(smem + row * 512 + (kbyte ^ ((row & 7) << 4)));
        }
#pragma unroll
        for (int i = 0; i < 2; ++i)
#pragma unroll
            for (int j = 0; j < 6; ++j)
                acc[i][j] = __builtin_amdgcn_mfma_f32_16x16x32_bf16(aW[j], bX[i], acc[i][j], 0, 0, 0);
    }
    __syncthreads();   // A region dead; reuse LDS as Y

    // ---- epilogue: bias + convert, write Y[32][776] bf16 (pad -> no conflicts) ----
#pragma unroll
    for (int i = 0; i < 2; ++i) {
        const int tok = i * 16 + fr;
#pragma unroll
        for (int j = 0; j < 6; ++j) {
            const int n0 = nb + j * 16 + fq * 4;
            float4 bias = *(const float4*)(qkv_b + n0);
            float bb[4] = {bias.x, bias.y, bias.z, bias.w};
            bf16x4 y;
#pragma unroll
            for (int r = 0; r < 4; ++r) y[r] = f2bf(acc[i][j][r] + bb[r]);
            *(bf16x4*)(smem + tok * 1552 + n0 * 2) = y;
        }
    }
    __syncthreads();

    // ---- attention: 16 threads per token (8 heads x 2 halves of Ch) ----
    {
        const int t = tid >> 4, sub = tid & 15;
        const int h = sub & 7, half = sub >> 3;
        const char* Yrow = smem + t * 1552;
        const float scale = 0.17677669529663687f;  // 1/sqrt(32)

        float q[16];
        {
            bf16x8 q0 = *(const bf16x8*)(Yrow + (h * 32 + half * 16) * 2);
            bf16x8 q1 = *(const bf16x8*)(Yrow + (h * 32 + half * 16 + 8) * 2);
#pragma unroll
            for (int c = 0; c < 8; ++c) { q[c] = bf2f(q0[c]); q[8 + c] = bf2f(q1[c]); }
        }
        float s[8];
#pragma unroll
        for (int g = 0; g < 8; ++g) {
            bf16x8 k0 = *(const bf16x8*)(Yrow + (256 + g * 32 + half * 16) * 2);
            bf16x8 k1 = *(const bf16x8*)(Yrow + (256 + g * 32 + half * 16 + 8) * 2);
            float p = 0.f;
#pragma unroll
            for (int c = 0; c < 8; ++c) { p += q[c] * bf2f(k0[c]); p += q[8 + c] * bf2f(k1[c]); }
            p += __shfl_xor(p, 8);   // combine the two c-halves (partner lane: same token/head)
            s[g] = p * scale;
        }
        float mx = s[0];
#pragma unroll
        for (int g = 1; g < 8; ++g) mx = fmaxf(mx, s[g]);
        float pw[8], psum = 0.f;
#pragma unroll
        for (int g = 0; g < 8; ++g) { pw[g] = __expf(s[g] - mx); psum += pw[g]; }
        const float inv = 1.f / psum;

        float o[16];
#pragma unroll
        for (int c = 0; c < 16; ++c) o[c] = 0.f;
#pragma unroll
        for (int g = 0; g < 8; ++g) {
            bf16x8 v0 = *(const bf16x8*)(Yrow + (512 + g * 32 + half * 16) * 2);
            bf16x8 v1 = *(const bf16x8*)(Yrow + (512 + g * 32 + half * 16 + 8) * 2);
#pragma unroll
            for (int c = 0; c < 8; ++c) { o[c] += pw[g] * bf2f(v0[c]); o[8 + c] += pw[g] * bf2f(v1[c]); }
        }

        // shuffled write: m = h*2048 + n ; row' = m>>3 ; col' = (m&7)*32 + ch
        const long tg = t0 + t;
        const long b  = tg >> 11;
        const int  n  = (int)(tg & 2047);
        const int  np = (h * 2048 + n) >> 3;
        const int  cp = (n & 7) * 32 + half * 16;
        short* dst = out2 + ((b * 2048 + np) * 256 + cp);
        bf16x8 o0, o1;
#pragma unroll
        for (int c = 0; c < 8; ++c) { o0[c] = f2bf(o[c] * inv); o1[c] = f2bf(o[8 + c] * inv); }
        *(bf16x8*)(dst)     = o0;
        *(bf16x8*)(dst + 8) = o1;
    }
}

// ---------------- K2: proj GEMM, out = out2 @ proj_w^T + proj_b ----------------
// 512 threads (8 waves), 64 tokens per block, full 256 output cols.
// Wave w owns n-rows [32w, 32w+32). Swapped operands again -> float4 stores.
__global__ __launch_bounds__(512, 4) void k2_proj(
    const short* __restrict__ out2,   // [131072][256] bf16
    const short* __restrict__ wp,     // [256][256] bf16
    const float* __restrict__ proj_b, // [256]
    float* __restrict__ out)          // [131072][256] fp32
{
    __shared__ __align__(16) char smem[64 * 512];  // 32KB swizzled bf16 tile
    const int tid  = threadIdx.x;
    const int lane = tid & 63;
    const int wave = tid >> 6;
    const long t0  = (long)blockIdx.x * 64;

    // stage out2 tile (64 rows x 512B), XOR swizzle
    {
        const int r = tid >> 3, sgm = tid & 7;
        const char* src = (const char*)out2 + (t0 + r) * 512 + sgm * 64;
        const int swz = (r & 7) << 4;
#pragma unroll
        for (int u = 0; u < 4; ++u) {
            bf16x8 v = *(const bf16x8*)(src + u * 16);
            const int off = sgm * 64 + u * 16;
            *(bf16x8*)(smem + r * 512 + (off ^ swz)) = v;
        }
    }
    __syncthreads();

    f32x4 acc[4][2];
#pragma unroll
    for (int i = 0; i < 4; ++i)
#pragma unroll
        for (int j = 0; j < 2; ++j) acc[i][j] = (f32x4){0.f, 0.f, 0.f, 0.f};

    const int fr = lane & 15, fq = lane >> 4;
    const int nb = wave * 32;
    const short* wp_base = wp + (nb + fr) * 256 + fq * 8;

#pragma unroll
    for (int ks = 0; ks < 8; ++ks) {
        bf16x8 aW[2], bX[4];
#pragma unroll
        for (int j = 0; j < 2; ++j)
            aW[j] = *(const bf16x8*)(wp_base + j * 16 * 256 + ks * 32);
        const int kbyte = (ks * 32 + fq * 8) * 2;
#pragma unroll
        for (int i = 0; i < 4; ++i) {
            const int row = i * 16 + fr;
            bX[i] = *(const bf16x8*)(smem + row * 512 + (kbyte ^ ((row & 7) << 4)));
        }
#pragma unroll
        for (int i = 0; i < 4; ++i)
#pragma unroll
            for (int j = 0; j < 2; ++j)
                acc[i][j] = __builtin_amdgcn_mfma_f32_16x16x32_bf16(aW[j], bX[i], acc[i][j], 0, 0, 0);
    }

    // epilogue: bias + contiguous float4 stores
#pragma unroll
    for (int i = 0; i < 4; ++i) {
        const long tok = t0 + i * 16 + fr;
#pragma unroll
        for (int j = 0; j < 2; ++j) {
            const int n0 = nb + j * 16 + fq * 4;
            float4 bias = *(const float4*)(proj_b + n0);
            float4 res;
            res.x = acc[i][j][0] + bias.x;
            res.y = acc[i][j][1] + bias.y;
            res.z = acc[i][j][2] + bias.z;
            res.w = acc[i][j][3] + bias.w;
            *(float4*)(out + tok * 256 + n0) = res;
        }
    }
}

extern "C" void kernel_launch(void* const* d_in, const int* in_sizes, int n_in,
                              void* d_out, int out_size, void* d_ws, size_t ws_size,
                              hipStream_t stream) {
    const float* x      = (const float*)d_in[0];
    const float* qkv_w  = (const float*)d_in[1];
    const float* qkv_b  = (const float*)d_in[2];
    const float* proj_w = (const float*)d_in[3];
    const float* proj_b = (const float*)d_in[4];
    float* out = (float*)d_out;

    char* ws = (char*)d_ws;
    short* out2  = (short*)ws;                               // 67,108,864 B
    short* wq_bf = (short*)(ws + 67108864);                  //    393,216 B
    short* wp_bf = (short*)(ws + 67108864 + 393216);         //    131,072 B

    k0_convert<<<1024, 256, 0, stream>>>(qkv_w, proj_w, wq_bf, wp_bf);
    k1_qkv_attn<<<4096, 512, 0, stream>>>(x, wq_bf, qkv_b, out2);
    k2_proj<<<2048, 512, 0, stream>>>(out2, wp_bf, proj_b, out);
}

// Round 2
// 446.807 us; speedup vs baseline: 1.0146x; 1.0146x over previous
//
#include <hip/hip_runtime.h>
#include <hip/hip_bf16.h>

// Problem constants
// B=64, N=2048, C=256, H=8, Ch=32, M = B*N = 131072
// qkv dim = 768 (s*256 + h*32 + ch)

typedef __attribute__((ext_vector_type(8))) short bf16x8;
typedef __attribute__((ext_vector_type(4))) short bf16x4;
typedef __attribute__((ext_vector_type(4))) float f32x4;

__device__ __forceinline__ short f2bf(float f) {
    unsigned u = __builtin_bit_cast(unsigned, f);
    unsigned r = (u + 0x7FFFu + ((u >> 16) & 1u)) >> 16;  // RNE
    return (short)r;
}
__device__ __forceinline__ float bf2f(short h) {
    unsigned u = ((unsigned)(unsigned short)h) << 16;
    return __builtin_bit_cast(float, u);
}

// ---------------- K0: convert weights fp32 -> bf16 ----------------
__global__ void k0_convert(const float* __restrict__ qkv_w,
                           const float* __restrict__ proj_w,
                           short* __restrict__ wq_bf,
                           short* __restrict__ wp_bf) {
    int i = blockIdx.x * 256 + threadIdx.x;   // grid covers 262144 exactly
    if (i < 196608) {
        wq_bf[i] = f2bf(qkv_w[i]);
    } else {
        int j = i - 196608;
        wp_bf[j] = f2bf(proj_w[j]);
    }
}

// ---------------- K1: fused QKV GEMM + head-attention ----------------
// 512 threads (8 waves), 32 tokens per block.
// v2: weight fragments double-buffered in registers (depth-1 prefetch),
// first-ks loads issued BEFORE the stage phase so L2 latency overlaps it.
__global__ __launch_bounds__(512, 4) void k1_qkv_attn(
    const float* __restrict__ x,      // [131072][256] fp32
    const short* __restrict__ wq,     // [768][256] bf16 bits
    const float* __restrict__ qkv_b,  // [768] fp32
    short* __restrict__ out2)         // [131072][256] bf16, shuffled layout
{
    __shared__ __align__(16) char smem[49664];  // A tile (16KB) aliased under Y tile (49.6KB)
    const int tid  = threadIdx.x;
    const int lane = tid & 63;
    const int wave = tid >> 6;
    const long t0  = (long)blockIdx.x * 32;

    const int fr = lane & 15, fq = lane >> 4;   // frag row select, k-quarter
    const int nb = wave * 96;                   // this wave's qkv-col base
    const short* wq_base = wq + (nb + fr) * 256 + fq * 8;

    // ---- issue ks=0 weight loads first: latency overlaps the stage phase ----
    bf16x8 wbuf[2][6];
#pragma unroll
    for (int j = 0; j < 6; ++j)
        wbuf[0][j] = *(const bf16x8*)(wq_base + j * 4096);

    // ---- stage A: x[t0..t0+32][0..256] fp32 -> bf16 LDS, XOR swizzle ----
    {
        const int r = tid >> 4, s = tid & 15;        // row 0..31, seg 0..15 (16 floats)
        const float4* src = (const float4*)(x + (t0 + r) * 256 + s * 16);
        float ff[16];
        float4 f0 = src[0], f1 = src[1], f2 = src[2], f3 = src[3];
        ff[0]=f0.x; ff[1]=f0.y; ff[2]=f0.z; ff[3]=f0.w;
        ff[4]=f1.x; ff[5]=f1.y; ff[6]=f1.z; ff[7]=f1.w;
        ff[8]=f2.x; ff[9]=f2.y; ff[10]=f2.z; ff[11]=f2.w;
        ff[12]=f3.x; ff[13]=f3.y; ff[14]=f3.z; ff[15]=f3.w;
        bf16x8 v0, v1;
#pragma unroll
        for (int i = 0; i < 8; ++i) { v0[i] = f2bf(ff[i]); v1[i] = f2bf(ff[8 + i]); }
        const int swz = (r & 7) << 4;
        *(bf16x8*)(smem + r * 512 + ((s * 32) ^ swz))      = v0;
        *(bf16x8*)(smem + r * 512 + ((s * 32 + 16) ^ swz)) = v1;
    }
    __syncthreads();

    // ---- MFMA main loop: K = 256 in 8 steps of 32, weight prefetch depth 1 ----
    f32x4 acc[2][6];
#pragma unroll
    for (int i = 0; i < 2; ++i)
#pragma unroll
        for (int j = 0; j < 6; ++j) acc[i][j] = (f32x4){0.f, 0.f, 0.f, 0.f};

#pragma unroll
    for (int ks = 0; ks < 8; ++ks) {
        const int cur = ks & 1, nxt = cur ^ 1;     // constant after full unroll
        if (ks + 1 < 8) {
#pragma unroll
            for (int j = 0; j < 6; ++j)
                wbuf[nxt][j] = *(const bf16x8*)(wq_base + j * 4096 + (ks + 1) * 32);
        }
        const int kbyte = (ks * 32 + fq * 8) * 2;
        bf16x8 bX[2];
#pragma unroll
        for (int i = 0; i < 2; ++i) {
            const int row = i * 16 + fr;
            bX[i] = *(const bf16x8*)(smem + row * 512 + (kbyte ^ ((row & 7) << 4)));
        }
#pragma unroll
        for (int i = 0; i < 2; ++i)
#pragma unroll
            for (int j = 0; j < 6; ++j)
                acc[i][j] = __builtin_amdgcn_mfma_f32_16x16x32_bf16(wbuf[cur][j], bX[i], acc[i][j], 0, 0, 0);
    }
    __syncthreads();   // A region dead; reuse LDS as Y

    // ---- epilogue: bias + convert, write Y[32][776] bf16 ----
#pragma unroll
    for (int i = 0; i < 2; ++i) {
        const int tok = i * 16 + fr;
#pragma unroll
        for (int j = 0; j < 6; ++j) {
            const int n0 = nb + j * 16 + fq * 4;
            float4 bias = *(const float4*)(qkv_b + n0);
            float bb[4] = {bias.x, bias.y, bias.z, bias.w};
            bf16x4 y;
#pragma unroll
            for (int r = 0; r < 4; ++r) y[r] = f2bf(acc[i][j][r] + bb[r]);
            *(bf16x4*)(smem + tok * 1552 + n0 * 2) = y;
        }
    }
    __syncthreads();

    // ---- attention: 16 threads per token (8 heads x 2 halves of Ch) ----
    {
        const int t = tid >> 4, sub = tid & 15;
        const int h = sub & 7, half = sub >> 3;
        const char* Yrow = smem + t * 1552;
        const float scale = 0.17677669529663687f;  // 1/sqrt(32)

        float q[16];
        {
            bf16x8 q0 = *(const bf16x8*)(Yrow + (h * 32 + half * 16) * 2);
            bf16x8 q1 = *(const bf16x8*)(Yrow + (h * 32 + half * 16 + 8) * 2);
#pragma unroll
            for (int c = 0; c < 8; ++c) { q[c] = bf2f(q0[c]); q[8 + c] = bf2f(q1[c]); }
        }
        float s[8];
#pragma unroll
        for (int g = 0; g < 8; ++g) {
            bf16x8 k0 = *(const bf16x8*)(Yrow + (256 + g * 32 + half * 16) * 2);
            bf16x8 k1 = *(const bf16x8*)(Yrow + (256 + g * 32 + half * 16 + 8) * 2);
            float p = 0.f;
#pragma unroll
            for (int c = 0; c < 8; ++c) { p += q[c] * bf2f(k0[c]); p += q[8 + c] * bf2f(k1[c]); }
            p += __shfl_xor(p, 8);   // combine the two c-halves (partner lane: same token/head)
            s[g] = p * scale;
        }
        float mx = s[0];
#pragma unroll
        for (int g = 1; g < 8; ++g) mx = fmaxf(mx, s[g]);
        float pw[8], psum = 0.f;
#pragma unroll
        for (int g = 0; g < 8; ++g) { pw[g] = __expf(s[g] - mx); psum += pw[g]; }
        const float inv = 1.f / psum;

        float o[16];
#pragma unroll
        for (int c = 0; c < 16; ++c) o[c] = 0.f;
#pragma unroll
        for (int g = 0; g < 8; ++g) {
            bf16x8 v0 = *(const bf16x8*)(Yrow + (512 + g * 32 + half * 16) * 2);
            bf16x8 v1 = *(const bf16x8*)(Yrow + (512 + g * 32 + half * 16 + 8) * 2);
#pragma unroll
            for (int c = 0; c < 8; ++c) { o[c] += pw[g] * bf2f(v0[c]); o[8 + c] += pw[g] * bf2f(v1[c]); }
        }

        // shuffled write: m = h*2048 + n ; row' = m>>3 ; col' = (m&7)*32 + ch
        const long tg = t0 + t;
        const long b  = tg >> 11;
        const int  n  = (int)(tg & 2047);
        const int  np = (h * 2048 + n) >> 3;
        const int  cp = (n & 7) * 32 + half * 16;
        short* dst = out2 + ((b * 2048 + np) * 256 + cp);
        bf16x8 o0, o1;
#pragma unroll
        for (int c = 0; c < 8; ++c) { o0[c] = f2bf(o[c] * inv); o1[c] = f2bf(o[8 + c] * inv); }
        *(bf16x8*)(dst)     = o0;
        *(bf16x8*)(dst + 8) = o1;
    }
}

// ---------------- K2: proj GEMM, out = out2 @ proj_w^T + proj_b ----------------
// v2: the wave's ENTIRE weight slice (16 frags = 64 VGPR) loaded upfront,
// overlapping the LDS staging; ks loop has zero global-memory dependence.
__global__ __launch_bounds__(512, 4) void k2_proj(
    const short* __restrict__ out2,   // [131072][256] bf16
    const short* __restrict__ wp,     // [256][256] bf16
    const float* __restrict__ proj_b, // [256]
    float* __restrict__ out)          // [131072][256] fp32
{
    __shared__ __align__(16) char smem[64 * 512];  // 32KB swizzled bf16 tile
    const int tid  = threadIdx.x;
    const int lane = tid & 63;
    const int wave = tid >> 6;
    const long t0  = (long)blockIdx.x * 64;

    const int fr = lane & 15, fq = lane >> 4;
    const int nb = wave * 32;
    const short* wp_base = wp + (nb + fr) * 256 + fq * 8;

    // ---- all 16 weight frags upfront (independent loads, one latency wait) ----
    bf16x8 wf[8][2];   // [ks][j], statically indexed below
#pragma unroll
    for (int ks = 0; ks < 8; ++ks)
#pragma unroll
        for (int j = 0; j < 2; ++j)
            wf[ks][j] = *(const bf16x8*)(wp_base + j * 4096 + ks * 32);

    // ---- stage out2 tile (64 rows x 512B), XOR swizzle ----
    {
        const int r = tid >> 3, sgm = tid & 7;
        const char* src = (const char*)out2 + (t0 + r) * 512 + sgm * 64;
        const int swz = (r & 7) << 4;
#pragma unroll
        for (int u = 0; u < 4; ++u) {
            bf16x8 v = *(const bf16x8*)(src + u * 16);
            const int off = sgm * 64 + u * 16;
            *(bf16x8*)(smem + r * 512 + (off ^ swz)) = v;
        }
    }
    __syncthreads();

    f32x4 acc[4][2];
#pragma unroll
    for (int i = 0; i < 4; ++i)
#pragma unroll
        for (int j = 0; j < 2; ++j) acc[i][j] = (f32x4){0.f, 0.f, 0.f, 0.f};

#pragma unroll
    for (int ks = 0; ks < 8; ++ks) {
        const int kbyte = (ks * 32 + fq * 8) * 2;
        bf16x8 bX[4];
#pragma unroll
        for (int i = 0; i < 4; ++i) {
            const int row = i * 16 + fr;
            bX[i] = *(const bf16x8*)(smem + row * 512 + (kbyte ^ ((row & 7) << 4)));
        }
#pragma unroll
        for (int i = 0; i < 4; ++i)
#pragma unroll
            for (int j = 0; j < 2; ++j)
                acc[i][j] = __builtin_amdgcn_mfma_f32_16x16x32_bf16(wf[ks][j], bX[i], acc[i][j], 0, 0, 0);
    }

    // ---- epilogue: bias + contiguous float4 stores ----
#pragma unroll
    for (int i = 0; i < 4; ++i) {
        const long tok = t0 + i * 16 + fr;
#pragma unroll
        for (int j = 0; j < 2; ++j) {
            const int n0 = nb + j * 16 + fq * 4;
            float4 bias = *(const float4*)(proj_b + n0);
            float4 res;
            res.x = acc[i][j][0] + bias.x;
            res.y = acc[i][j][1] + bias.y;
            res.z = acc[i][j][2] + bias.z;
            res.w = acc[i][j][3] + bias.w;
            *(float4*)(out + tok * 256 + n0) = res;
        }
    }
}

extern "C" void kernel_launch(void* const* d_in, const int* in_sizes, int n_in,
                              void* d_out, int out_size, void* d_ws, size_t ws_size,
                              hipStream_t stream) {
    const float* x      = (const float*)d_in[0];
    const float* qkv_w  = (const float*)d_in[1];
    const float* qkv_b  = (const float*)d_in[2];
    const float* proj_w = (const float*)d_in[3];
    const float* proj_b = (const float*)d_in[4];
    float* out = (float*)d_out;

    char* ws = (char*)d_ws;
    short* out2  = (short*)ws;                               // 67,108,864 B
    short* wq_bf = (short*)(ws + 67108864);                  //    393,216 B
    short* wp_bf = (short*)(ws + 67108864 + 393216);         //    131,072 B

    k0_convert<<<1024, 256, 0, stream>>>(qkv_w, proj_w, wq_bf, wp_bf);
    k1_qkv_attn<<<4096, 512, 0, stream>>>(x, wq_bf, qkv_b, out2);
    k2_proj<<<2048, 512, 0, stream>>>(out2, wp_bf, proj_b, out);
}